// Round 2
// baseline (2256.122 us; speedup 1.0000x reference)
//
#include <hip/hip_runtime.h>
#include <math.h>

// Problem constants: B=8, N=1024, C=256, KS=512, H=8, HD=64
// ws layout (float offsets): stats[32] | q[8192*512] | k[8192*512] | Qt[64][64][1024] | Kb[64][1024][64]
#define S_STAT 0
#define S_Q    32
#define S_K    (32 + 4194304)
#define S_QT   (32 + 8388608)
#define S_KB   (32 + 12582912)

__device__ __forceinline__ float wave_sum(float v) {
#pragma unroll
    for (int m = 1; m < 64; m <<= 1) v += __shfl_xor(v, m);
    return v;
}

// DPP cross-lane term: returns src moved by CTRL; masked/invalid lanes yield `oldv`.
template<int CTRL, int RM>
__device__ __forceinline__ float dpp_term(float v, float oldv) {
    return __int_as_float(__builtin_amdgcn_update_dpp(
        __float_as_int(oldv), __float_as_int(v), CTRL, RM, 0xf, false));
}

// gfx9 wave64 reduction on the VALU pipe (no LDS): row_shr 1/2/4/8, bcast15, bcast31.
__device__ __forceinline__ float wave_sum_dpp(float x) {
    x += dpp_term<0x111, 0xf>(x, 0.f);
    x += dpp_term<0x112, 0xf>(x, 0.f);
    x += dpp_term<0x114, 0xf>(x, 0.f);
    x += dpp_term<0x118, 0xf>(x, 0.f);
    x += dpp_term<0x142, 0xa>(x, 0.f);
    x += dpp_term<0x143, 0xc>(x, 0.f);
    return __int_as_float(__builtin_amdgcn_readlane(__float_as_int(x), 63));
}
__device__ __forceinline__ float wave_max_dpp(float x) {
    x = fmaxf(x, dpp_term<0x111, 0xf>(x, x));
    x = fmaxf(x, dpp_term<0x112, 0xf>(x, x));
    x = fmaxf(x, dpp_term<0x114, 0xf>(x, x));
    x = fmaxf(x, dpp_term<0x118, 0xf>(x, x));
    x = fmaxf(x, dpp_term<0x142, 0xa>(x, x));
    x = fmaxf(x, dpp_term<0x143, 0xc>(x, x));
    return __int_as_float(__builtin_amdgcn_readlane(__float_as_int(x), 63));
}

__global__ __launch_bounds__(64) void k0_zero(float* __restrict__ ws) {
    if (threadIdx.x < 32) ws[S_STAT + threadIdx.x] = 0.0f;
}

// K1: q = x @ qw^T (j-tiles 0..7), k = x @ kw^T (j-tiles 8..15). 64x64 tile per WG.
__global__ __launch_bounds__(256) void k1_gemm(const float* __restrict__ x,
                                               const float* __restrict__ qw,
                                               const float* __restrict__ kw,
                                               float* __restrict__ ws) {
    __shared__ float xa[64][20];
    __shared__ float wb[64][20];
    __shared__ float red[8];
    const int t  = threadIdx.x;
    const int n0 = blockIdx.x * 64;
    const int ty = blockIdx.y;
    const bool is_q = (ty < 8);
    const int j0 = (ty & 7) * 64;
    const float* __restrict__ W = is_q ? qw : kw;
    float* __restrict__ outp = ws + (is_q ? S_Q : S_K);

    const int lr = t >> 2;
    const int lc = (t & 3) * 4;
    const int tr = (t >> 4) * 4;
    const int tc = (t & 15) * 4;

    float acc[4][4];
#pragma unroll
    for (int i = 0; i < 4; ++i)
#pragma unroll
        for (int j = 0; j < 4; ++j) acc[i][j] = 0.0f;

    for (int kc = 0; kc < 256; kc += 16) {
        __syncthreads();
        *(float4*)(&xa[lr][lc]) = *(const float4*)(x + (size_t)(n0 + lr) * 256 + kc + lc);
        *(float4*)(&wb[lr][lc]) = *(const float4*)(W + (size_t)(j0 + lr) * 256 + kc + lc);
        __syncthreads();
#pragma unroll
        for (int k4 = 0; k4 < 16; k4 += 4) {
            float4 av[4], bv[4];
#pragma unroll
            for (int i = 0; i < 4; ++i) av[i] = *(const float4*)(&xa[tr + i][k4]);
#pragma unroll
            for (int j = 0; j < 4; ++j) bv[j] = *(const float4*)(&wb[tc + j][k4]);
#pragma unroll
            for (int i = 0; i < 4; ++i)
#pragma unroll
                for (int j = 0; j < 4; ++j)
                    acc[i][j] = fmaf(av[i].x, bv[j].x,
                                fmaf(av[i].y, bv[j].y,
                                fmaf(av[i].z, bv[j].z,
                                fmaf(av[i].w, bv[j].w, acc[i][j]))));
        }
    }
#pragma unroll
    for (int i = 0; i < 4; ++i) {
        float4 o = make_float4(acc[i][0], acc[i][1], acc[i][2], acc[i][3]);
        *(float4*)(outp + (size_t)(n0 + tr + i) * 512 + j0 + tc) = o;
    }
    float s1 = 0.0f, s2 = 0.0f;
#pragma unroll
    for (int i = 0; i < 4; ++i)
#pragma unroll
        for (int j = 0; j < 4; ++j) { s1 += acc[i][j]; s2 += acc[i][j] * acc[i][j]; }
    s1 = wave_sum(s1);
    s2 = wave_sum(s2);
    if ((t & 63) == 0) { red[t >> 6] = s1; red[4 + (t >> 6)] = s2; }
    __syncthreads();
    if (t == 0) {
        float t1 = red[0] + red[1] + red[2] + red[3];
        float t2 = red[4] + red[5] + red[6] + red[7];
        const int base = (is_q ? 0 : 16) + (ty & 7);
        atomicAdd(ws + S_STAT + base, t1);
        atomicAdd(ws + S_STAT + base + 8, t2);
    }
}

// K3: BN(train) + L2-normalize per 64-vector.
// z=0: Q -> Qt[bh][d][n] (transposed via LDS).  z=1: K*(1/16) -> Kb[bh][n][d].
__global__ __launch_bounds__(256) void k3_norm(const float* __restrict__ bnw,
                                               const float* __restrict__ bnb,
                                               float* __restrict__ ws) {
    __shared__ float tile[64][65];
    const int t = threadIdx.x;
    const int w = t >> 6, l = t & 63;
    const int nb = blockIdx.x;
    const int bh = blockIdx.y;
    const int b = bh >> 3, h = bh & 7;
    const int z = blockIdx.z;
    const float* __restrict__ in = ws + (z ? S_K : S_Q);
    const float* st = ws + S_STAT + (z ? 16 : 0);
    const float inv_m = 1.0f / 524288.0f;
    const float mean  = st[h] * inv_m;
    const float var   = st[8 + h] * inv_m - mean * mean;
    const float alpha = rsqrtf(var + 1e-5f) * bnw[h];
    const float beta  = bnb[h] - mean * alpha;

    if (z == 0) {
#pragma unroll 1
        for (int i = 0; i < 16; ++i) {
            const int r = w * 16 + i;
            const int n = nb * 64 + r;
            float v = in[(size_t)(b * 1024 + n) * 512 + h * 64 + l];
            v = fmaf(v, alpha, beta);
            float ss = wave_sum(v * v);
            v /= fmaxf(sqrtf(ss), 1e-12f);
            tile[l][r] = v;
        }
        __syncthreads();
        float* qt = ws + S_QT + (size_t)bh * 65536;
        const int d = t >> 2;
#pragma unroll
        for (int i = 0; i < 4; ++i) {
            const int j = (t & 3) * 4 + i * 16;
            float4 o = make_float4(tile[d][j], tile[d][j + 1], tile[d][j + 2], tile[d][j + 3]);
            *(float4*)(qt + d * 1024 + nb * 64 + j) = o;
        }
    } else {
        float* kb = ws + S_KB;
#pragma unroll 1
        for (int i = 0; i < 16; ++i) {
            const int r = w * 16 + i;
            const int n = nb * 64 + r;
            float v = in[(size_t)(b * 1024 + n) * 512 + h * 64 + l];
            v = fmaf(v, alpha, beta);
            float ss = wave_sum(v * v);
            v = v / fmaxf(sqrtf(ss), 1e-12f) * 0.0625f;   // fold 1/sqrt(256)
            kb[(size_t)(bh * 1024 + n) * 64 + l] = v;
        }
    }
}

// K4: block = (bh, 64-column tile). 512 threads = 8 waves x 8 cols.
// Lane l owns rows n = j0*256 + l*4 + i (b128-friendly). K via uniform scalar
// loads from global (no LDS). Reductions via DPP (no LDS). Output written as
// 256 B coalesced segments via a swizzled 32 KB LDS transpose tile.
__global__ __launch_bounds__(512, 2) void k4_attn(const float* __restrict__ ws,
                                                  float* __restrict__ out) {
    __shared__ float lds[8192];   // 32 KB: q-chunk [8 d][1024 n]  /  epilogue [128][64]
    const int t  = threadIdx.x;
    const int l  = t & 63;
    const int wu = __builtin_amdgcn_readfirstlane(t >> 6);
    const int bid = blockIdx.x;
    const int bh = bid & 63;          // same-bh blocks stride 64 apart -> same XCD (bid%8)
    const int mt = bid >> 6;
    const int b = bh >> 3, h = bh & 7;
    const int m0 = mt * 64;
    const float* __restrict__ qt = ws + S_QT + (size_t)bh * 65536;
    const float* __restrict__ kb = ws + S_KB + ((size_t)bh * 1024 + m0 + wu * 8) * 64;

    float acc[128];   // [j0][i][c] : rows j0*256 + l*4 + i, cols wu*8 + c
#pragma unroll
    for (int i = 0; i < 128; ++i) acc[i] = 0.f;

    float4 pf[4];
#pragma unroll
    for (int i = 0; i < 4; ++i)
        pf[i] = *(const float4*)(qt + (size_t)(i * 512 + t) * 4);

#pragma unroll 1
    for (int ch = 0; ch < 8; ++ch) {
        __syncthreads();
#pragma unroll
        for (int i = 0; i < 4; ++i)
            *(float4*)(lds + (i * 512 + t) * 4) = pf[i];
        if (ch < 7) {
            const float* nq = qt + (size_t)(ch + 1) * 8192;
#pragma unroll
            for (int i = 0; i < 4; ++i)
                pf[i] = *(const float4*)(nq + (size_t)(i * 512 + t) * 4);
        }
        __syncthreads();
#pragma unroll
        for (int dd = 0; dd < 8; ++dd) {
            float kv[8];
#pragma unroll
            for (int c = 0; c < 8; ++c) kv[c] = kb[c * 64 + ch * 8 + dd];   // uniform -> s_load
            float4 qv[4];
#pragma unroll
            for (int j0 = 0; j0 < 4; ++j0)
                qv[j0] = *(const float4*)(lds + dd * 1024 + j0 * 256 + l * 4);
#pragma unroll
            for (int j0 = 0; j0 < 4; ++j0) {
                const float* qf = (const float*)&qv[j0];
#pragma unroll
                for (int i = 0; i < 4; ++i)
#pragma unroll
                    for (int c = 0; c < 8; ++c)
                        acc[(j0 * 4 + i) * 8 + c] = fmaf(qf[i], kv[c], acc[(j0 * 4 + i) * 8 + c]);
            }
        }
    }

    // --- sparsemax per column: guaranteed bisection + exact recompute ---
    float tau[8];
#pragma unroll 1
    for (int c = 0; c < 8; ++c) {
        float vmax = -1e30f, vsum = 0.f;
#pragma unroll
        for (int j = 0; j < 16; ++j) { float z = acc[j * 8 + c]; vmax = fmaxf(vmax, z); vsum += z; }
        vmax = wave_max_dpp(vmax);
        vsum = wave_sum_dpp(vsum);
        float lo = fmaxf(vmax - 1.0f, (vsum - 1.0f) * (1.0f / 1024.0f));  // lo <= tau*
        float hi = vmax - (1.0f / 1024.0f);                               // f(hi) <= 0
#pragma unroll 1
        for (int it = 0; it < 12; ++it) {
            const float mid = 0.5f * (lo + hi);
            float s = 0.f;
#pragma unroll
            for (int j = 0; j < 16; ++j) s += fmaxf(acc[j * 8 + c] - mid, 0.f);
            s = wave_sum_dpp(s);
            if (s > 1.0f) lo = mid; else hi = mid;   // uniform (readlane) -> no divergence
        }
        float cnt = 0.f, ssum = 0.f;
#pragma unroll
        for (int j = 0; j < 16; ++j) {
            float z = acc[j * 8 + c];
            if (z > lo) { cnt += 1.f; ssum += z; }
        }
        cnt = wave_sum_dpp(cnt);
        ssum = wave_sum_dpp(ssum);
        tau[c] = (ssum - 1.0f) / cnt;
    }

    // --- epilogue: 8 chunks of 128 rows; swizzled LDS transpose; 256 B stores ---
    const int la = l & 31;
    const int halfl = l >> 5;
    float* __restrict__ ob = out + (size_t)b * 1024 * 8192 + h * 1024 + m0;
#pragma unroll 1
    for (int ch = 0; ch < 8; ++ch) {
        const int j0 = ch >> 1;
        const int half = ch & 1;
        __syncthreads();
        if (halfl == half) {              // rows n = j0*256 + half*128 + la*4 + i
#pragma unroll
            for (int i = 0; i < 4; ++i) {
                const int r = la * 4 + i;                 // local row 0..127
#pragma unroll
                for (int sh = 0; sh < 2; ++sh) {
                    const int s = wu * 2 + sh;            // float4 slot 0..15
                    float4 v;
                    float* vf = (float*)&v;
#pragma unroll
                    for (int jj = 0; jj < 4; ++jj) {
                        const int c = sh * 4 + jj;
                        vf[jj] = fmaxf(acc[(j0 * 4 + i) * 8 + c] - tau[c], 0.f);
                    }
                    *(float4*)(lds + r * 64 + ((s ^ la) & 15) * 4) = v;   // XOR swizzle
                }
            }
        }
        __syncthreads();
#pragma unroll
        for (int k = 0; k < 4; ++k) {
            const int sl = k * 512 + t;
            const int r = sl >> 4;
            const int sr = sl & 15;
            float4 v = *(const float4*)(lds + r * 64 + ((sr ^ (r >> 2)) & 15) * 4);
            *(float4*)(ob + (size_t)(ch * 128 + r) * 8192 + sr * 4) = v;
        }
    }
}

extern "C" void kernel_launch(void* const* d_in, const int* in_sizes, int n_in,
                              void* d_out, int out_size, void* d_ws, size_t ws_size,
                              hipStream_t stream) {
    (void)in_sizes; (void)n_in; (void)out_size; (void)ws_size;
    const float* x   = (const float*)d_in[0];
    const float* qw  = (const float*)d_in[1];
    const float* kw  = (const float*)d_in[2];
    const float* bnw = (const float*)d_in[3];
    const float* bnb = (const float*)d_in[4];
    float* ws  = (float*)d_ws;
    float* out = (float*)d_out;

    hipLaunchKernelGGL(k0_zero, dim3(1), dim3(64), 0, stream, ws);
    hipLaunchKernelGGL(k1_gemm, dim3(128, 16), dim3(256), 0, stream, x, qw, kw, ws);
    hipLaunchKernelGGL(k3_norm, dim3(16, 64, 2), dim3(256), 0, stream, bnw, bnb, ws);
    hipLaunchKernelGGL(k4_attn, dim3(1024), dim3(512), 0, stream, ws, out);
}

// Round 3
// 625.263 us; speedup vs baseline: 3.6083x; 3.6083x over previous
//
#include <hip/hip_runtime.h>
#include <math.h>

// Problem constants: B=8, N=1024, C=256, KS=512, H=8, HD=64
// ws layout (float offsets): stats[32] | q[8192*512] | k[8192*512] | Qt[64][64][1024] | Kb[64][1024][64]
#define S_STAT 0
#define S_Q    32
#define S_K    (32 + 4194304)
#define S_QT   (32 + 8388608)
#define S_KB   (32 + 12582912)

__device__ __forceinline__ float wave_sum(float v) {
#pragma unroll
    for (int m = 1; m < 64; m <<= 1) v += __shfl_xor(v, m);
    return v;
}

// DPP cross-lane term: returns src moved by CTRL; masked/invalid lanes yield `oldv`.
template<int CTRL, int RM>
__device__ __forceinline__ float dpp_term(float v, float oldv) {
    return __int_as_float(__builtin_amdgcn_update_dpp(
        __float_as_int(oldv), __float_as_int(v), CTRL, RM, 0xf, false));
}

// gfx9 wave64 reduction on the VALU pipe (no LDS): row_shr 1/2/4/8, bcast15, bcast31.
__device__ __forceinline__ float wave_sum_dpp(float x) {
    x += dpp_term<0x111, 0xf>(x, 0.f);
    x += dpp_term<0x112, 0xf>(x, 0.f);
    x += dpp_term<0x114, 0xf>(x, 0.f);
    x += dpp_term<0x118, 0xf>(x, 0.f);
    x += dpp_term<0x142, 0xa>(x, 0.f);
    x += dpp_term<0x143, 0xc>(x, 0.f);
    return __int_as_float(__builtin_amdgcn_readlane(__float_as_int(x), 63));
}
__device__ __forceinline__ float wave_max_dpp(float x) {
    x = fmaxf(x, dpp_term<0x111, 0xf>(x, x));
    x = fmaxf(x, dpp_term<0x112, 0xf>(x, x));
    x = fmaxf(x, dpp_term<0x114, 0xf>(x, x));
    x = fmaxf(x, dpp_term<0x118, 0xf>(x, x));
    x = fmaxf(x, dpp_term<0x142, 0xa>(x, x));
    x = fmaxf(x, dpp_term<0x143, 0xc>(x, x));
    return __int_as_float(__builtin_amdgcn_readlane(__float_as_int(x), 63));
}

__global__ __launch_bounds__(64) void k0_zero(float* __restrict__ ws) {
    if (threadIdx.x < 32) ws[S_STAT + threadIdx.x] = 0.0f;
}

// K1: q = x @ qw^T (j-tiles 0..7), k = x @ kw^T (j-tiles 8..15). 64x64 tile per WG.
__global__ __launch_bounds__(256) void k1_gemm(const float* __restrict__ x,
                                               const float* __restrict__ qw,
                                               const float* __restrict__ kw,
                                               float* __restrict__ ws) {
    __shared__ float xa[64][20];
    __shared__ float wb[64][20];
    __shared__ float red[8];
    const int t  = threadIdx.x;
    const int n0 = blockIdx.x * 64;
    const int ty = blockIdx.y;
    const bool is_q = (ty < 8);
    const int j0 = (ty & 7) * 64;
    const float* __restrict__ W = is_q ? qw : kw;
    float* __restrict__ outp = ws + (is_q ? S_Q : S_K);

    const int lr = t >> 2;
    const int lc = (t & 3) * 4;
    const int tr = (t >> 4) * 4;
    const int tc = (t & 15) * 4;

    float acc[4][4];
#pragma unroll
    for (int i = 0; i < 4; ++i)
#pragma unroll
        for (int j = 0; j < 4; ++j) acc[i][j] = 0.0f;

    for (int kc = 0; kc < 256; kc += 16) {
        __syncthreads();
        *(float4*)(&xa[lr][lc]) = *(const float4*)(x + (size_t)(n0 + lr) * 256 + kc + lc);
        *(float4*)(&wb[lr][lc]) = *(const float4*)(W + (size_t)(j0 + lr) * 256 + kc + lc);
        __syncthreads();
#pragma unroll
        for (int k4 = 0; k4 < 16; k4 += 4) {
            float4 av[4], bv[4];
#pragma unroll
            for (int i = 0; i < 4; ++i) av[i] = *(const float4*)(&xa[tr + i][k4]);
#pragma unroll
            for (int j = 0; j < 4; ++j) bv[j] = *(const float4*)(&wb[tc + j][k4]);
#pragma unroll
            for (int i = 0; i < 4; ++i)
#pragma unroll
                for (int j = 0; j < 4; ++j)
                    acc[i][j] = fmaf(av[i].x, bv[j].x,
                                fmaf(av[i].y, bv[j].y,
                                fmaf(av[i].z, bv[j].z,
                                fmaf(av[i].w, bv[j].w, acc[i][j]))));
        }
    }
#pragma unroll
    for (int i = 0; i < 4; ++i) {
        float4 o = make_float4(acc[i][0], acc[i][1], acc[i][2], acc[i][3]);
        *(float4*)(outp + (size_t)(n0 + tr + i) * 512 + j0 + tc) = o;
    }
    float s1 = 0.0f, s2 = 0.0f;
#pragma unroll
    for (int i = 0; i < 4; ++i)
#pragma unroll
        for (int j = 0; j < 4; ++j) { s1 += acc[i][j]; s2 += acc[i][j] * acc[i][j]; }
    s1 = wave_sum(s1);
    s2 = wave_sum(s2);
    if ((t & 63) == 0) { red[t >> 6] = s1; red[4 + (t >> 6)] = s2; }
    __syncthreads();
    if (t == 0) {
        float t1 = red[0] + red[1] + red[2] + red[3];
        float t2 = red[4] + red[5] + red[6] + red[7];
        const int base = (is_q ? 0 : 16) + (ty & 7);
        atomicAdd(ws + S_STAT + base, t1);
        atomicAdd(ws + S_STAT + base + 8, t2);
    }
}

// K3: BN(train) + L2-normalize per 64-vector.
// z=0: Q -> Qt[bh][d][n] (transposed via LDS).  z=1: K*(1/16) -> Kb[bh][n][d].
__global__ __launch_bounds__(256) void k3_norm(const float* __restrict__ bnw,
                                               const float* __restrict__ bnb,
                                               float* __restrict__ ws) {
    __shared__ float tile[64][65];
    const int t = threadIdx.x;
    const int w = t >> 6, l = t & 63;
    const int nb = blockIdx.x;
    const int bh = blockIdx.y;
    const int b = bh >> 3, h = bh & 7;
    const int z = blockIdx.z;
    const float* __restrict__ in = ws + (z ? S_K : S_Q);
    const float* st = ws + S_STAT + (z ? 16 : 0);
    const float inv_m = 1.0f / 524288.0f;
    const float mean  = st[h] * inv_m;
    const float var   = st[8 + h] * inv_m - mean * mean;
    const float alpha = rsqrtf(var + 1e-5f) * bnw[h];
    const float beta  = bnb[h] - mean * alpha;

    if (z == 0) {
#pragma unroll 1
        for (int i = 0; i < 16; ++i) {
            const int r = w * 16 + i;
            const int n = nb * 64 + r;
            float v = in[(size_t)(b * 1024 + n) * 512 + h * 64 + l];
            v = fmaf(v, alpha, beta);
            float ss = wave_sum(v * v);
            v /= fmaxf(sqrtf(ss), 1e-12f);
            tile[l][r] = v;
        }
        __syncthreads();
        float* qt = ws + S_QT + (size_t)bh * 65536;
        const int d = t >> 2;
#pragma unroll
        for (int i = 0; i < 4; ++i) {
            const int j = (t & 3) * 4 + i * 16;
            float4 o = make_float4(tile[d][j], tile[d][j + 1], tile[d][j + 2], tile[d][j + 3]);
            *(float4*)(qt + d * 1024 + nb * 64 + j) = o;
        }
    } else {
        float* kb = ws + S_KB;
#pragma unroll 1
        for (int i = 0; i < 16; ++i) {
            const int r = w * 16 + i;
            const int n = nb * 64 + r;
            float v = in[(size_t)(b * 1024 + n) * 512 + h * 64 + l];
            v = fmaf(v, alpha, beta);
            float ss = wave_sum(v * v);
            v = v / fmaxf(sqrtf(ss), 1e-12f) * 0.0625f;   // fold 1/sqrt(256)
            kb[(size_t)(bh * 1024 + n) * 64 + l] = v;
        }
    }
}

// K4: block = (bh, 64-column tile). 512 threads = 8 waves x 8 cols.
// Lane l owns rows n = j0*256 + l*4 + i. K via uniform scalar loads (no LDS).
// Reductions via DPP (no LDS). Output via swizzled 32 KB LDS transpose,
// 256 B coalesced segments.
// NOTE: every acc[]/tau[] index MUST be compile-time static — a single
// runtime index demotes the whole array to scratch (round-2: 12 GB spill
// traffic). Hence full unrolls on the sparsemax-column and epilogue loops.
__global__ __launch_bounds__(512, 2) void k4_attn(const float* __restrict__ ws,
                                                  float* __restrict__ out) {
    __shared__ float lds[8192];   // 32 KB: q-chunk [8 d][1024 n]  /  epilogue [128][64]
    const int t  = threadIdx.x;
    const int l  = t & 63;
    const int wu = __builtin_amdgcn_readfirstlane(t >> 6);
    const int bid = blockIdx.x;
    const int bh = bid & 63;          // same-bh blocks stride 64 apart -> same XCD (bid%8)
    const int mt = bid >> 6;
    const int b = bh >> 3, h = bh & 7;
    const int m0 = mt * 64;
    const float* __restrict__ qt = ws + S_QT + (size_t)bh * 65536;
    const float* __restrict__ kb = ws + S_KB + ((size_t)bh * 1024 + m0 + wu * 8) * 64;

    float acc[128];   // [j0][i][c] : rows j0*256 + l*4 + i, cols wu*8 + c
#pragma unroll
    for (int i = 0; i < 128; ++i) acc[i] = 0.f;

    float4 pf[4];
#pragma unroll
    for (int i = 0; i < 4; ++i)
        pf[i] = *(const float4*)(qt + (size_t)(i * 512 + t) * 4);

#pragma unroll 1
    for (int ch = 0; ch < 8; ++ch) {
        __syncthreads();
#pragma unroll
        for (int i = 0; i < 4; ++i)
            *(float4*)(lds + (i * 512 + t) * 4) = pf[i];
        if (ch < 7) {
            const float* nq = qt + (size_t)(ch + 1) * 8192;
#pragma unroll
            for (int i = 0; i < 4; ++i)
                pf[i] = *(const float4*)(nq + (size_t)(i * 512 + t) * 4);
        }
        __syncthreads();
#pragma unroll
        for (int dd = 0; dd < 8; ++dd) {
            float kv[8];
#pragma unroll
            for (int c = 0; c < 8; ++c) kv[c] = kb[c * 64 + ch * 8 + dd];   // uniform -> s_load
            float4 qv[4];
#pragma unroll
            for (int j0 = 0; j0 < 4; ++j0)
                qv[j0] = *(const float4*)(lds + dd * 1024 + j0 * 256 + l * 4);
#pragma unroll
            for (int j0 = 0; j0 < 4; ++j0) {
                const float* qf = (const float*)&qv[j0];
#pragma unroll
                for (int i = 0; i < 4; ++i)
#pragma unroll
                    for (int c = 0; c < 8; ++c)
                        acc[(j0 * 4 + i) * 8 + c] = fmaf(qf[i], kv[c], acc[(j0 * 4 + i) * 8 + c]);
            }
        }
    }

    // --- sparsemax per column: guaranteed bisection + exact recompute ---
    // Fully unrolled over c so acc/z/tau indices stay static (no scratch).
    float tau[8];
#pragma unroll
    for (int c = 0; c < 8; ++c) {
        float z[16];
#pragma unroll
        for (int j = 0; j < 16; ++j) z[j] = acc[j * 8 + c];
        float vmax = z[0], vsum = z[0];
#pragma unroll
        for (int j = 1; j < 16; ++j) { vmax = fmaxf(vmax, z[j]); vsum += z[j]; }
        vmax = wave_max_dpp(vmax);
        vsum = wave_sum_dpp(vsum);
        float lo = fmaxf(vmax - 1.0f, (vsum - 1.0f) * (1.0f / 1024.0f));  // lo <= tau*
        float hi = vmax - (1.0f / 1024.0f);                               // f(hi) <= 0
#pragma unroll 1
        for (int it = 0; it < 12; ++it) {
            const float mid = 0.5f * (lo + hi);
            float s = 0.f;
#pragma unroll
            for (int j = 0; j < 16; ++j) s += fmaxf(z[j] - mid, 0.f);
            s = wave_sum_dpp(s);
            if (s > 1.0f) lo = mid; else hi = mid;   // uniform (readlane) -> no divergence
        }
        float cnt = 0.f, ssum = 0.f;
#pragma unroll
        for (int j = 0; j < 16; ++j) {
            if (z[j] > lo) { cnt += 1.f; ssum += z[j]; }
        }
        cnt = wave_sum_dpp(cnt);
        ssum = wave_sum_dpp(ssum);
        tau[c] = (ssum - 1.0f) / cnt;
    }

    // --- epilogue: 8 chunks of 128 rows; swizzled LDS transpose; 256 B stores.
    //     Fully unrolled so acc/tau indices stay static. ---
    const int la = l & 31;
    const int halfl = l >> 5;
    float* __restrict__ ob = out + (size_t)b * 1024 * 8192 + h * 1024 + m0;
#pragma unroll
    for (int ch = 0; ch < 8; ++ch) {
        const int j0 = ch >> 1;
        const int half = ch & 1;
        __syncthreads();
        if (halfl == half) {              // rows n = j0*256 + half*128 + la*4 + i
#pragma unroll
            for (int i = 0; i < 4; ++i) {
                const int r = la * 4 + i;                 // local row 0..127
#pragma unroll
                for (int sh = 0; sh < 2; ++sh) {
                    const int s = wu * 2 + sh;            // float4 slot 0..15
                    float4 v;
                    float* vf = (float*)&v;
#pragma unroll
                    for (int jj = 0; jj < 4; ++jj) {
                        const int c = sh * 4 + jj;
                        vf[jj] = fmaxf(acc[(j0 * 4 + i) * 8 + c] - tau[c], 0.f);
                    }
                    *(float4*)(lds + r * 64 + ((s ^ la) & 15) * 4) = v;   // XOR swizzle
                }
            }
        }
        __syncthreads();
#pragma unroll
        for (int k = 0; k < 4; ++k) {
            const int sl = k * 512 + t;
            const int r = sl >> 4;
            const int sr = sl & 15;
            float4 v = *(const float4*)(lds + r * 64 + ((sr ^ (r >> 2)) & 15) * 4);
            *(float4*)(ob + (size_t)(ch * 128 + r) * 8192 + sr * 4) = v;
        }
    }
}

extern "C" void kernel_launch(void* const* d_in, const int* in_sizes, int n_in,
                              void* d_out, int out_size, void* d_ws, size_t ws_size,
                              hipStream_t stream) {
    (void)in_sizes; (void)n_in; (void)out_size; (void)ws_size;
    const float* x   = (const float*)d_in[0];
    const float* qw  = (const float*)d_in[1];
    const float* kw  = (const float*)d_in[2];
    const float* bnw = (const float*)d_in[3];
    const float* bnb = (const float*)d_in[4];
    float* ws  = (float*)d_ws;
    float* out = (float*)d_out;

    hipLaunchKernelGGL(k0_zero, dim3(1), dim3(64), 0, stream, ws);
    hipLaunchKernelGGL(k1_gemm, dim3(128, 16), dim3(256), 0, stream, x, qw, kw, ws);
    hipLaunchKernelGGL(k3_norm, dim3(16, 64, 2), dim3(256), 0, stream, bnw, bnb, ws);
    hipLaunchKernelGGL(k4_attn, dim3(1024), dim3(512), 0, stream, ws, out);
}

// Round 5
// 493.109 us; speedup vs baseline: 4.5753x; 1.2680x over previous
//
#include <hip/hip_runtime.h>
#include <math.h>

// Problem constants: B=8, N=1024, C=256, KS=512, H=8, HD=64
// ws layout (float offsets): stats[32] | q fp32[8192*512] | k fp32[8192*512] |
//   bf16 planes (ushort, 4 x 4194304): QH | QL | KH | KL, plain P[bh][n][d].
#define S_STAT 0
#define S_Q    32
#define S_K    (32 + 4194304)
#define S_PL   (32 + 8388608)
#define PLSZ   4194304

typedef unsigned short ushort;
typedef unsigned int uint;
typedef __attribute__((ext_vector_type(8))) short short8;
typedef __attribute__((ext_vector_type(16))) float floatx16;

__device__ __forceinline__ float wave_sum(float v) {
#pragma unroll
    for (int m = 1; m < 64; m <<= 1) v += __shfl_xor(v, m);
    return v;
}

// round-to-nearest-even fp32 -> bf16
__device__ __forceinline__ ushort f2bf(float f) {
    uint u = __float_as_uint(f);
    uint r = (u + 0x7fffu + ((u >> 16) & 1u)) >> 16;
    return (ushort)r;
}

__global__ __launch_bounds__(64) void k0_zero(float* __restrict__ ws) {
    if (threadIdx.x < 32) ws[S_STAT + threadIdx.x] = 0.0f;
}

// K1: q = x @ qw^T (ty 0..7), k = x @ kw^T (ty 8..15). 64x64 tile per WG.
// (Exact round-3 code — proven correct 3x.)
__global__ __launch_bounds__(256) void k1_gemm(const float* __restrict__ x,
                                               const float* __restrict__ qw,
                                               const float* __restrict__ kw,
                                               float* __restrict__ ws) {
    __shared__ float xa[64][20];
    __shared__ float wb[64][20];
    __shared__ float red[8];
    const int t  = threadIdx.x;
    const int n0 = blockIdx.x * 64;
    const int ty = blockIdx.y;
    const bool is_q = (ty < 8);
    const int j0 = (ty & 7) * 64;
    const float* __restrict__ W = is_q ? qw : kw;
    float* __restrict__ outp = ws + (is_q ? S_Q : S_K);

    const int lr = t >> 2;
    const int lc = (t & 3) * 4;
    const int tr = (t >> 4) * 4;
    const int tc = (t & 15) * 4;

    float acc[4][4];
#pragma unroll
    for (int i = 0; i < 4; ++i)
#pragma unroll
        for (int j = 0; j < 4; ++j) acc[i][j] = 0.0f;

    for (int kc = 0; kc < 256; kc += 16) {
        __syncthreads();
        *(float4*)(&xa[lr][lc]) = *(const float4*)(x + (size_t)(n0 + lr) * 256 + kc + lc);
        *(float4*)(&wb[lr][lc]) = *(const float4*)(W + (size_t)(j0 + lr) * 256 + kc + lc);
        __syncthreads();
#pragma unroll
        for (int k4 = 0; k4 < 16; k4 += 4) {
            float4 av[4], bv[4];
#pragma unroll
            for (int i = 0; i < 4; ++i) av[i] = *(const float4*)(&xa[tr + i][k4]);
#pragma unroll
            for (int j = 0; j < 4; ++j) bv[j] = *(const float4*)(&wb[tc + j][k4]);
#pragma unroll
            for (int i = 0; i < 4; ++i)
#pragma unroll
                for (int j = 0; j < 4; ++j)
                    acc[i][j] = fmaf(av[i].x, bv[j].x,
                                fmaf(av[i].y, bv[j].y,
                                fmaf(av[i].z, bv[j].z,
                                fmaf(av[i].w, bv[j].w, acc[i][j]))));
        }
    }
#pragma unroll
    for (int i = 0; i < 4; ++i) {
        float4 o = make_float4(acc[i][0], acc[i][1], acc[i][2], acc[i][3]);
        *(float4*)(outp + (size_t)(n0 + tr + i) * 512 + j0 + tc) = o;
    }
    float s1 = 0.0f, s2 = 0.0f;
#pragma unroll
    for (int i = 0; i < 4; ++i)
#pragma unroll
        for (int j = 0; j < 4; ++j) { s1 += acc[i][j]; s2 += acc[i][j] * acc[i][j]; }
    s1 = wave_sum(s1);
    s2 = wave_sum(s2);
    if ((t & 63) == 0) { red[t >> 6] = s1; red[4 + (t >> 6)] = s2; }
    __syncthreads();
    if (t == 0) {
        float t1 = red[0] + red[1] + red[2] + red[3];
        float t2 = red[4] + red[5] + red[6] + red[7];
        const int base = (is_q ? 0 : 16) + (ty & 7);
        atomicAdd(ws + S_STAT + base, t1);
        atomicAdd(ws + S_STAT + base + 8, t2);
    }
}

// K3: BN(train) + L2-normalize per 64-vector, then split into bf16 hi/lo planes
// (K pre-scaled by 1/16), plain n-major layout P[bh][n][d] (NO swizzle).
__global__ __launch_bounds__(256) void k3_norm(const float* __restrict__ bnw,
                                               const float* __restrict__ bnb,
                                               float* __restrict__ ws) {
    const int t = threadIdx.x;
    const int w = t >> 6, l = t & 63;
    const int nb = blockIdx.x;
    const int bh = blockIdx.y;
    const int b = bh >> 3, h = bh & 7;
    const int z = blockIdx.z;
    const float* __restrict__ in = ws + (z ? S_K : S_Q);
    const float* st = ws + S_STAT + (z ? 16 : 0);
    ushort* __restrict__ PH = (ushort*)(ws + S_PL) + (z ? 2 * PLSZ : 0) + (size_t)bh * 65536;
    ushort* __restrict__ PL = PH + PLSZ;
    const float inv_m = 1.0f / 524288.0f;
    const float mean  = st[h] * inv_m;
    const float var   = st[8 + h] * inv_m - mean * mean;
    const float alpha = rsqrtf(var + 1e-5f) * bnw[h];
    const float beta  = bnb[h] - mean * alpha;
    const float scale = z ? 0.0625f : 1.0f;   // fold 1/sqrt(256) into K

#pragma unroll 1
    for (int i = 0; i < 16; ++i) {
        const int n = nb * 64 + w * 16 + i;
        float v = in[(size_t)(b * 1024 + n) * 512 + h * 64 + l];
        v = fmaf(v, alpha, beta);
        float ss = wave_sum(v * v);
        v = v / fmaxf(sqrtf(ss), 1e-12f) * scale;
        ushort h16 = f2bf(v);
        float hif = __uint_as_float(((uint)h16) << 16);
        ushort l16 = f2bf(v - hif);
        const int idx = n * 64 + l;           // plain layout
        PH[idx] = h16;
        PL[idx] = l16;
    }
}

// K4: block = (bh, 32-m tile), 256 thr = 4 waves (wave w = n-quarter of 256).
// MINIMAL-ASSUMPTION version: fragments loaded DIRECTLY from global (no LDS
// staging, no swizzle, no async DMA, no manual waitcnt). Split-bf16 MFMA
// 32x32x16: acc += Qh*Kh + Ql*Kh + Qh*Kl.
// Operand maps under test: A row m = lane&31, k = (lane>>5)*8+j (contiguous);
// B col n = lane&31, same k map; C/D col = lane&31,
// row = (e&3) + 8*(e>>2) + 4*(lane>>5)   [guide: measured m74/m101].
// All acc[]/kf[] indices compile-time static (round-2 scratch lesson).
__global__ __launch_bounds__(256, 2) void k4_attn(const float* __restrict__ ws,
                                                  float* __restrict__ out) {
    __shared__ float part[4][4][32];
    const int t = threadIdx.x;
    const int l = t & 63;
    const int w = t >> 6;
    const int bid = blockIdx.x;
    const int bh = bid & 63;          // same-bh blocks share an XCD (bid%8) for L2 reuse
    const int mt = bid >> 6;          // 0..31
    const int b = bh >> 3, h = bh & 7;
    const int m0 = mt * 32;
    const ushort* __restrict__ QH = (const ushort*)(ws + S_PL);
    const ushort* __restrict__ QL = QH + PLSZ;
    const ushort* __restrict__ KH = QH + 2 * PLSZ;
    const ushort* __restrict__ KL = QH + 3 * PLSZ;

    const int row = l & 31;           // A-row / B-col within the 32-tile
    const int kb8 = l >> 5;           // k-half: k = kb8*8 + j

    // ---- K fragments (B operand): K row = m0+row, d = ks*16 + kb8*8 + j ----
    short8 kf[2][4];
#pragma unroll
    for (int ks = 0; ks < 4; ++ks) {
        const size_t off = (size_t)(bh * 1024 + m0 + row) * 64 + ks * 16 + kb8 * 8;
        kf[0][ks] = *(const short8*)(KH + off);
        kf[1][ks] = *(const short8*)(KL + off);
    }

    floatx16 acc[8] = {};

    // ---- K-loop: 8 n-tiles of 32 rows; Q fragments direct from global ----
#pragma unroll
    for (int r = 0; r < 8; ++r) {
        const size_t qoff = (size_t)(bh * 1024 + w * 256 + r * 32 + row) * 64 + kb8 * 8;
#pragma unroll
        for (int ks = 0; ks < 4; ++ks) {
            short8 ah = *(const short8*)(QH + qoff + ks * 16);
            short8 al = *(const short8*)(QL + qoff + ks * 16);
            acc[r] = __builtin_amdgcn_mfma_f32_32x32x16_bf16(ah, kf[0][ks], acc[r], 0, 0, 0);
            acc[r] = __builtin_amdgcn_mfma_f32_32x32x16_bf16(al, kf[0][ks], acc[r], 0, 0, 0);
            acc[r] = __builtin_amdgcn_mfma_f32_32x32x16_bf16(ah, kf[1][ks], acc[r], 0, 0, 0);
        }
    }

    // ---- sparsemax per column m = m0 + (l&31) over n = 1024 ----
    const int col = row;
    float vmaxl = -1e30f, vsuml = 0.f;
#pragma unroll
    for (int r = 0; r < 8; ++r)
#pragma unroll
        for (int e = 0; e < 16; ++e) {
            const float zz = acc[r][e];
            vmaxl = fmaxf(vmaxl, zz);
            vsuml += zz;
        }
    vmaxl = fmaxf(vmaxl, __shfl_xor(vmaxl, 32));
    vsuml += __shfl_xor(vsuml, 32);
    if (l < 32) { part[2][w][col] = vmaxl; part[3][w][col] = vsuml; }
    __syncthreads();
    float vmax = fmaxf(fmaxf(part[2][0][col], part[2][1][col]),
                       fmaxf(part[2][2][col], part[2][3][col]));
    float vsum = part[3][0][col] + part[3][1][col] + part[3][2][col] + part[3][3][col];

    float lo = fmaxf(vmax - 1.0f, (vsum - 1.0f) * (1.0f / 1024.0f));   // lo <= tau*
    float hi = vmax - (1.0f / 1024.0f);                                // f(hi) <= 0 -> hi >= tau*
#pragma unroll 1
    for (int it = 0; it < 12; ++it) {
        const float mid = 0.5f * (lo + hi);
        float sl = 0.f;
#pragma unroll
        for (int r = 0; r < 8; ++r)
#pragma unroll
            for (int e = 0; e < 16; ++e) sl += fmaxf(acc[r][e] - mid, 0.f);
        sl += __shfl_xor(sl, 32);
        if (l < 32) part[it & 1][w][col] = sl;
        __syncthreads();   // double-buffered partials: one barrier per iteration
        const float s = part[it & 1][0][col] + part[it & 1][1][col]
                      + part[it & 1][2][col] + part[it & 1][3][col];
        if (s > 1.0f) lo = mid; else hi = mid;   // identical on all lanes
    }
    // exact recompute on {z > lo}; inclusion of ties within the bracket
    // shifts tau by <= bracket width (3e-5) -- far under threshold.
    float cntl = 0.f, ssml = 0.f;
#pragma unroll
    for (int r = 0; r < 8; ++r)
#pragma unroll
        for (int e = 0; e < 16; ++e) {
            const float zz = acc[r][e];
            if (zz > lo) { cntl += 1.f; ssml += zz; }
        }
    cntl += __shfl_xor(cntl, 32);
    ssml += __shfl_xor(ssml, 32);
    if (l < 32) { part[2][w][col] = cntl; part[3][w][col] = ssml; }
    __syncthreads();
    const float cnt  = part[2][0][col] + part[2][1][col] + part[2][2][col] + part[2][3][col];
    const float ssum = part[3][0][col] + part[3][1][col] + part[3][2][col] + part[3][3][col];
    const float tau = (ssum - 1.0f) / cnt;

    // ---- epilogue: direct stores; lanes 0-31 / 32-63 = two 128 B segments ----
    float* __restrict__ ob = out + (size_t)b * 1024 * 8192 + h * 1024 + m0 + col;
    const int nbase = w * 256 + 4 * kb8;
#pragma unroll
    for (int r = 0; r < 8; ++r)
#pragma unroll
        for (int e = 0; e < 16; ++e) {
            const int n = nbase + r * 32 + (e & 3) + 8 * (e >> 2);
            ob[(size_t)n * 8192] = fmaxf(acc[r][e] - tau, 0.f);
        }
}

extern "C" void kernel_launch(void* const* d_in, const int* in_sizes, int n_in,
                              void* d_out, int out_size, void* d_ws, size_t ws_size,
                              hipStream_t stream) {
    (void)in_sizes; (void)n_in; (void)out_size; (void)ws_size;
    const float* x   = (const float*)d_in[0];
    const float* qw  = (const float*)d_in[1];
    const float* kw  = (const float*)d_in[2];
    const float* bnw = (const float*)d_in[3];
    const float* bnb = (const float*)d_in[4];
    float* ws  = (float*)d_ws;
    float* out = (float*)d_out;

    hipLaunchKernelGGL(k0_zero, dim3(1), dim3(64), 0, stream, ws);
    hipLaunchKernelGGL(k1_gemm, dim3(128, 16), dim3(256), 0, stream, x, qw, kw, ws);
    hipLaunchKernelGGL(k3_norm, dim3(16, 64, 2), dim3(256), 0, stream, bnw, bnb, ws);
    hipLaunchKernelGGL(k4_attn, dim3(2048), dim3(256), 0, stream, ws, out);
}

// Round 6
// 470.142 us; speedup vs baseline: 4.7988x; 1.0489x over previous
//
#include <hip/hip_runtime.h>
#include <math.h>

// Problem constants: B=8, N=1024, C=256, KS=512, H=8, HD=64
// ws layout (float offsets): stats[32] | q fp32[8192*512] | k fp32[8192*512] |
//   bf16 planes (ushort): QH|QL|KH|KL (4 x PLSZ)  then  XH|XL (2 x 2097152)
//   then WH|WL (2 x 262144; cols 0..511 = qw rows, 512..1023 = kw rows).
#define S_STAT 0
#define S_Q    32
#define S_K    (32 + 4194304)
#define S_PL   (32 + 8388608)
#define PLSZ   4194304

typedef unsigned short ushort;
typedef unsigned int uint;
typedef __attribute__((ext_vector_type(8))) short short8;
typedef __attribute__((ext_vector_type(16))) float floatx16;

__device__ __forceinline__ float wave_sum(float v) {
#pragma unroll
    for (int m = 1; m < 64; m <<= 1) v += __shfl_xor(v, m);
    return v;
}

// round-to-nearest-even fp32 -> bf16
__device__ __forceinline__ ushort f2bf(float f) {
    uint u = __float_as_uint(f);
    uint r = (u + 0x7fffu + ((u >> 16) & 1u)) >> 16;
    return (ushort)r;
}

__global__ __launch_bounds__(64) void k0_zero(float* __restrict__ ws) {
    if (threadIdx.x < 32) ws[S_STAT + threadIdx.x] = 0.0f;
}

// k_pre: split x (blocks 0..2047), qw (2048..2175), kw (2176..2303) into
// bf16 hi/lo planes. Each thread: one float4 -> ushort4 hi + ushort4 lo.
__global__ __launch_bounds__(256) void k_pre(const float* __restrict__ x,
                                             const float* __restrict__ qw,
                                             const float* __restrict__ kw,
                                             float* __restrict__ ws) {
    ushort* base = (ushort*)(ws + S_PL) + 4 * PLSZ;
    ushort* XH = base;
    ushort* XL = XH + 2097152;
    ushort* WH = XL + 2097152;
    ushort* WL = WH + 262144;
    const int bid = blockIdx.x;
    const int tid = threadIdx.x;
    const float* __restrict__ src;
    ushort *dh, *dl;
    int idx4;
    if (bid < 2048)      { src = x;  dh = XH;           dl = XL;           idx4 = bid * 256 + tid; }
    else if (bid < 2176) { src = qw; dh = WH;           dl = WL;           idx4 = (bid - 2048) * 256 + tid; }
    else                 { src = kw; dh = WH + 131072;  dl = WL + 131072;  idx4 = (bid - 2176) * 256 + tid; }
    const float4 v = *(const float4*)(src + (size_t)idx4 * 4);
    ushort4 hv, lv;
    {
        hv.x = f2bf(v.x); lv.x = f2bf(v.x - __uint_as_float(((uint)hv.x) << 16));
        hv.y = f2bf(v.y); lv.y = f2bf(v.y - __uint_as_float(((uint)hv.y) << 16));
        hv.z = f2bf(v.z); lv.z = f2bf(v.z - __uint_as_float(((uint)hv.z) << 16));
        hv.w = f2bf(v.w); lv.w = f2bf(v.w - __uint_as_float(((uint)hv.w) << 16));
    }
    *(ushort4*)(dh + (size_t)idx4 * 4) = hv;
    *(ushort4*)(dl + (size_t)idx4 * 4) = lv;
}

// K1 (MFMA): [8192 x 256] x [256 x 1024] -> q (cols 0..511) / k (cols 512..1023),
// split-bf16 3-term. Block = 128x128 tile, 4 waves (wave w: rows w&1, cols w>>1).
// Fragments direct from global (k4-proven pattern). Per-head stats via wave
// reduce + atomics (each wave's 64-col span = exactly one head).
__global__ __launch_bounds__(256, 2) void k1_mfma(float* __restrict__ ws) {
    const ushort* base = (const ushort*)(ws + S_PL) + 4 * PLSZ;
    const ushort* __restrict__ XH = base;
    const ushort* __restrict__ XL = XH + 2097152;
    const ushort* __restrict__ WH = XL + 2097152;
    const ushort* __restrict__ WL = WH + 262144;
    const int t = threadIdx.x;
    const int l = t & 63;
    const int w = t >> 6;
    const int rw = w & 1, cw = w >> 1;
    const int row0 = blockIdx.x * 128 + rw * 64;   // n base of this wave
    const int col0 = blockIdx.y * 128 + cw * 64;   // j base of this wave (one head)
    const int lane31 = l & 31;
    const int kb8 = (l >> 5) * 8;

    floatx16 acc[2][2] = {};
#pragma unroll 4
    for (int kc = 0; kc < 256; kc += 16) {
        short8 ah[2], al[2], bh[2], bl[2];
#pragma unroll
        for (int rt = 0; rt < 2; ++rt) {
            const size_t o = (size_t)(row0 + rt * 32 + lane31) * 256 + kc + kb8;
            ah[rt] = *(const short8*)(XH + o);
            al[rt] = *(const short8*)(XL + o);
        }
#pragma unroll
        for (int ct = 0; ct < 2; ++ct) {
            const size_t o = (size_t)(col0 + ct * 32 + lane31) * 256 + kc + kb8;
            bh[ct] = *(const short8*)(WH + o);
            bl[ct] = *(const short8*)(WL + o);
        }
#pragma unroll
        for (int rt = 0; rt < 2; ++rt)
#pragma unroll
            for (int ct = 0; ct < 2; ++ct) {
                acc[rt][ct] = __builtin_amdgcn_mfma_f32_32x32x16_bf16(ah[rt], bh[ct], acc[rt][ct], 0, 0, 0);
                acc[rt][ct] = __builtin_amdgcn_mfma_f32_32x32x16_bf16(al[rt], bh[ct], acc[rt][ct], 0, 0, 0);
                acc[rt][ct] = __builtin_amdgcn_mfma_f32_32x32x16_bf16(ah[rt], bl[ct], acc[rt][ct], 0, 0, 0);
            }
    }

    const bool is_q = (col0 < 512);
    float* __restrict__ outp = ws + (is_q ? S_Q : S_K);
    const int cbase = col0 & 511;
    const int rsub = 4 * (l >> 5);
    float s1 = 0.f, s2 = 0.f;
#pragma unroll
    for (int rt = 0; rt < 2; ++rt)
#pragma unroll
        for (int ct = 0; ct < 2; ++ct)
#pragma unroll
            for (int e = 0; e < 16; ++e) {
                const int r = row0 + rt * 32 + rsub + (e & 3) + 8 * (e >> 2);
                const int c = cbase + ct * 32 + lane31;
                const float v = acc[rt][ct][e];
                outp[(size_t)r * 512 + c] = v;
                s1 += v; s2 += v * v;
            }
    s1 = wave_sum(s1);
    s2 = wave_sum(s2);
    if (l == 0) {
        const int head = (cbase >> 6) & 7;
        const int sb = (is_q ? 0 : 16) + head;
        atomicAdd(ws + S_STAT + sb, s1);
        atomicAdd(ws + S_STAT + sb + 8, s2);
    }
}

// K3: BN(train) + L2-normalize per 64-vector, then split into bf16 hi/lo planes
// (K pre-scaled by 1/16), plain n-major layout P[bh][n][d].
__global__ __launch_bounds__(256) void k3_norm(const float* __restrict__ bnw,
                                               const float* __restrict__ bnb,
                                               float* __restrict__ ws) {
    const int t = threadIdx.x;
    const int w = t >> 6, l = t & 63;
    const int nb = blockIdx.x;
    const int bh = blockIdx.y;
    const int b = bh >> 3, h = bh & 7;
    const int z = blockIdx.z;
    const float* __restrict__ in = ws + (z ? S_K : S_Q);
    const float* st = ws + S_STAT + (z ? 16 : 0);
    ushort* __restrict__ PH = (ushort*)(ws + S_PL) + (z ? 2 * PLSZ : 0) + (size_t)bh * 65536;
    ushort* __restrict__ PL = PH + PLSZ;
    const float inv_m = 1.0f / 524288.0f;
    const float mean  = st[h] * inv_m;
    const float var   = st[8 + h] * inv_m - mean * mean;
    const float alpha = rsqrtf(var + 1e-5f) * bnw[h];
    const float beta  = bnb[h] - mean * alpha;
    const float scale = z ? 0.0625f : 1.0f;   // fold 1/sqrt(256) into K

#pragma unroll 1
    for (int i = 0; i < 16; ++i) {
        const int n = nb * 64 + w * 16 + i;
        float v = in[(size_t)(b * 1024 + n) * 512 + h * 64 + l];
        v = fmaf(v, alpha, beta);
        float ss = wave_sum(v * v);
        v = v / fmaxf(sqrtf(ss), 1e-12f) * scale;
        ushort h16 = f2bf(v);
        float hif = __uint_as_float(((uint)h16) << 16);
        ushort l16 = f2bf(v - hif);
        const int idx = n * 64 + l;           // plain layout
        PH[idx] = h16;
        PL[idx] = l16;
    }
}

// K4: block = (bh, 32-m tile), 256 thr = 4 waves (wave w = n-quarter of 256).
// Fragments direct from global; split-bf16 MFMA 32x32x16 (Qh*Kh + Ql*Kh + Qh*Kl).
// C/D: col = lane&31 = m, row = (e&3)+8*(e>>2)+4*(lane>>5)  [HW-verified r5].
__global__ __launch_bounds__(256, 2) void k4_attn(const float* __restrict__ ws,
                                                  float* __restrict__ out) {
    __shared__ float part[4][4][32];
    const int t = threadIdx.x;
    const int l = t & 63;
    const int w = t >> 6;
    const int bid = blockIdx.x;
    const int bh = bid & 63;          // same-bh blocks share an XCD (bid%8) for L2 reuse
    const int mt = bid >> 6;          // 0..31
    const int b = bh >> 3, h = bh & 7;
    const int m0 = mt * 32;
    const ushort* __restrict__ QH = (const ushort*)(ws + S_PL);
    const ushort* __restrict__ QL = QH + PLSZ;
    const ushort* __restrict__ KH = QH + 2 * PLSZ;
    const ushort* __restrict__ KL = QH + 3 * PLSZ;

    const int row = l & 31;
    const int kb8 = l >> 5;

    short8 kf[2][4];
#pragma unroll
    for (int ks = 0; ks < 4; ++ks) {
        const size_t off = (size_t)(bh * 1024 + m0 + row) * 64 + ks * 16 + kb8 * 8;
        kf[0][ks] = *(const short8*)(KH + off);
        kf[1][ks] = *(const short8*)(KL + off);
    }

    floatx16 acc[8] = {};

#pragma unroll
    for (int r = 0; r < 8; ++r) {
        const size_t qoff = (size_t)(bh * 1024 + w * 256 + r * 32 + row) * 64 + kb8 * 8;
#pragma unroll
        for (int ks = 0; ks < 4; ++ks) {
            short8 ah = *(const short8*)(QH + qoff + ks * 16);
            short8 al = *(const short8*)(QL + qoff + ks * 16);
            acc[r] = __builtin_amdgcn_mfma_f32_32x32x16_bf16(ah, kf[0][ks], acc[r], 0, 0, 0);
            acc[r] = __builtin_amdgcn_mfma_f32_32x32x16_bf16(al, kf[0][ks], acc[r], 0, 0, 0);
            acc[r] = __builtin_amdgcn_mfma_f32_32x32x16_bf16(ah, kf[1][ks], acc[r], 0, 0, 0);
        }
    }

    // ---- sparsemax per column m = m0 + (l&31) over n = 1024 ----
    const int col = row;
    float vmaxl = -1e30f, vsuml = 0.f;
#pragma unroll
    for (int r = 0; r < 8; ++r)
#pragma unroll
        for (int e = 0; e < 16; ++e) {
            const float zz = acc[r][e];
            vmaxl = fmaxf(vmaxl, zz);
            vsuml += zz;
        }
    vmaxl = fmaxf(vmaxl, __shfl_xor(vmaxl, 32));
    vsuml += __shfl_xor(vsuml, 32);
    if (l < 32) { part[2][w][col] = vmaxl; part[3][w][col] = vsuml; }
    __syncthreads();
    float vmax = fmaxf(fmaxf(part[2][0][col], part[2][1][col]),
                       fmaxf(part[2][2][col], part[2][3][col]));
    float vsum = part[3][0][col] + part[3][1][col] + part[3][2][col] + part[3][3][col];

    float lo = fmaxf(vmax - 1.0f, (vsum - 1.0f) * (1.0f / 1024.0f));   // lo <= tau*
    float hi = vmax - (1.0f / 1024.0f);                                // f(hi) <= 0
#pragma unroll 1
    for (int it = 0; it < 12; ++it) {
        const float mid = 0.5f * (lo + hi);
        float sl = 0.f;
#pragma unroll
        for (int r = 0; r < 8; ++r)
#pragma unroll
            for (int e = 0; e < 16; ++e) sl += fmaxf(acc[r][e] - mid, 0.f);
        sl += __shfl_xor(sl, 32);
        if (l < 32) part[it & 1][w][col] = sl;
        __syncthreads();   // double-buffered partials: one barrier per iteration
        const float s = part[it & 1][0][col] + part[it & 1][1][col]
                      + part[it & 1][2][col] + part[it & 1][3][col];
        if (s > 1.0f) lo = mid; else hi = mid;
    }
    float cntl = 0.f, ssml = 0.f;
#pragma unroll
    for (int r = 0; r < 8; ++r)
#pragma unroll
        for (int e = 0; e < 16; ++e) {
            const float zz = acc[r][e];
            if (zz > lo) { cntl += 1.f; ssml += zz; }
        }
    cntl += __shfl_xor(cntl, 32);
    ssml += __shfl_xor(ssml, 32);
    if (l < 32) { part[2][w][col] = cntl; part[3][w][col] = ssml; }
    __syncthreads();
    const float cnt  = part[2][0][col] + part[2][1][col] + part[2][2][col] + part[2][3][col];
    const float ssum = part[3][0][col] + part[3][1][col] + part[3][2][col] + part[3][3][col];
    const float tau = (ssum - 1.0f) / cnt;

    float* __restrict__ ob = out + (size_t)b * 1024 * 8192 + h * 1024 + m0 + col;
    const int nbase = w * 256 + 4 * kb8;
#pragma unroll
    for (int r = 0; r < 8; ++r)
#pragma unroll
        for (int e = 0; e < 16; ++e) {
            const int n = nbase + r * 32 + (e & 3) + 8 * (e >> 2);
            ob[(size_t)n * 8192] = fmaxf(acc[r][e] - tau, 0.f);
        }
}

extern "C" void kernel_launch(void* const* d_in, const int* in_sizes, int n_in,
                              void* d_out, int out_size, void* d_ws, size_t ws_size,
                              hipStream_t stream) {
    (void)in_sizes; (void)n_in; (void)out_size; (void)ws_size;
    const float* x   = (const float*)d_in[0];
    const float* qw  = (const float*)d_in[1];
    const float* kw  = (const float*)d_in[2];
    const float* bnw = (const float*)d_in[3];
    const float* bnb = (const float*)d_in[4];
    float* ws  = (float*)d_ws;
    float* out = (float*)d_out;

    hipLaunchKernelGGL(k0_zero, dim3(1), dim3(64), 0, stream, ws);
    hipLaunchKernelGGL(k_pre, dim3(2304), dim3(256), 0, stream, x, qw, kw, ws);
    hipLaunchKernelGGL(k1_mfma, dim3(64, 8), dim3(256), 0, stream, ws);
    hipLaunchKernelGGL(k3_norm, dim3(16, 64, 2), dim3(256), 0, stream, bnw, bnb, ws);
    hipLaunchKernelGGL(k4_attn, dim3(2048), dim3(256), 0, stream, ws, out);
}